// Round 3
// baseline (715.740 us; speedup 1.0000x reference)
//
#include <hip/hip_runtime.h>
#include <stdint.h>

#define NB 64
#define NO 32
#define NI 512
#define ND 64

typedef __attribute__((ext_vector_type(8))) short short8;
typedef __attribute__((ext_vector_type(4))) float f32x4;

// async global->LDS DMA, 16 B/lane. Global addr per-lane; LDS base wave-uniform,
// lane i lands at base + 16*i (m104/m108 semantics).
#define GL2LDS(g, s) __builtin_amdgcn_global_load_lds( \
    (const __attribute__((address_space(1))) void*)(g), \
    (__attribute__((address_space(3))) void*)(s), 16, 0, 0)

__device__ __forceinline__ float blo(unsigned int u) {
    union { unsigned int i; float f; } v; v.i = u << 16; return v.f;
}
__device__ __forceinline__ float bhi(unsigned int u) {
    union { unsigned int i; float f; } v; v.i = u & 0xFFFF0000u; return v.f;
}
__device__ __forceinline__ unsigned short f2bf(float f) {
    union { float f; unsigned int i; } v; v.f = f;
    return (unsigned short)((v.i + 0x7FFFu + ((v.i >> 16) & 1u)) >> 16);
}
__device__ __forceinline__ short8 pack8(const float4 a, const float4 b) {
    short8 r;
    r[0] = (short)f2bf(a.x); r[1] = (short)f2bf(a.y);
    r[2] = (short)f2bf(a.z); r[3] = (short)f2bf(a.w);
    r[4] = (short)f2bf(b.x); r[5] = (short)f2bf(b.y);
    r[6] = (short)f2bf(b.z); r[7] = (short)f2bf(b.w);
    return r;
}
__device__ __forceinline__ void ld_a(float4 r[4], const float* __restrict__ p) {
    r[0] = *(const float4*)(p);
    r[1] = *(const float4*)(p + 4);
    r[2] = *(const float4*)(p + 32);
    r[3] = *(const float4*)(p + 36);
}

// K1: x_hat = W x, stored bf16 in PERMUTED d-order: d' = 4c + td  (d = 16 td + c).
// Also accumulates s0[b][o][d'] = sum_i x_hat (fp32, atomic partials per
// block) -- this is routing-iter-0's c-weighted sum up to the uniform 1/32
// factor, so the entire route<0> pass (a full 128 MiB xh read) is eliminated.
__global__ __launch_bounds__(256) void k_gemm(const float* __restrict__ x,
                                              const float* __restrict__ w,
                                              unsigned short* __restrict__ xh,
                                              float* __restrict__ s0) {
    __shared__ float Wl[3][4096];            // 48 KB, triple-buffered W tiles
    const int o  = blockIdx.x & 31;
    const int ig = blockIdx.x >> 5;
    const int t  = threadIdx.x;
    const int wv = t >> 6;
    const int l  = t & 63;
    const int q  = l >> 4;
    const int c  = l & 15;

    const float* wbase = w + ((size_t)o * NI + ig * 8) * 4096;

    auto stage = [&](int buf, int ii) {
        const float* src = wbase + (size_t)ii * 4096;
        #pragma unroll
        for (int k = 0; k < 4; ++k) {
            const int s = wv * 256 + k * 64 + l;
            const int r = s >> 4;
            const int g = (s & 15) ^ (r & 15);
            GL2LDS(src + r * 64 + g * 4, &Wl[buf][(wv * 256 + k * 64) * 4]);
        }
    };

    const float* ap0 = x + ((size_t)(16 * wv + c) * NI + ig * 8) * 64 + q * 8;
    float4 ra[4], na[4];
    ld_a(ra, ap0);
    stage(0, 0);
    stage(1, 1);

    f32x4 psum[4];
    #pragma unroll
    for (int td = 0; td < 4; ++td) psum[td] = (f32x4){0.f, 0.f, 0.f, 0.f};

    uint2 cst[4];
    #pragma unroll
    for (int ii = 0; ii < 8; ++ii) {
        __syncthreads();                     // stage(ii) visible; drains only iter-old vmcnt
        if (ii > 0) {                        // store iter ii-1's C (fresh stores AFTER barrier)
            #pragma unroll
            for (int rr = 0; rr < 4; ++rr) {
                const int bq = 16 * wv + 4 * q + rr;
                *(uint2*)(xh + (((size_t)o * NB + bq) * NI + (ig * 8 + ii - 1)) * ND + 4 * c) = cst[rr];
            }
        }
        if (ii < 6) stage((ii + 2) % 3, ii + 2);
        if (ii < 7) ld_a(na, ap0 + (ii + 1) * 64);

        const float* Wb = Wl[ii % 3];
        const short8 a0 = pack8(ra[0], ra[1]);
        const short8 a1 = pack8(ra[2], ra[3]);
        f32x4 acc[4];
        #pragma unroll
        for (int td = 0; td < 4; ++td) {
            const int r = 16 * td + c;
            const float4 f0 = *(const float4*)&Wb[(r * 16 + ((2 * q)     ^ c)) * 4];
            const float4 f1 = *(const float4*)&Wb[(r * 16 + ((2 * q + 1) ^ c)) * 4];
            const float4 f2 = *(const float4*)&Wb[(r * 16 + ((2 * q + 8) ^ c)) * 4];
            const float4 f3 = *(const float4*)&Wb[(r * 16 + ((2 * q + 9) ^ c)) * 4];
            const short8 b0 = pack8(f0, f1);
            const short8 b1 = pack8(f2, f3);
            f32x4 z = {0.f, 0.f, 0.f, 0.f};
            z = __builtin_amdgcn_mfma_f32_16x16x32_bf16(a0, b0, z, 0, 0, 0);
            z = __builtin_amdgcn_mfma_f32_16x16x32_bf16(a1, b1, z, 0, 0, 0);
            acc[td] = z;
            psum[td] += z;                   // s0 partial over this block's 8 i's
        }
        #pragma unroll
        for (int rr = 0; rr < 4; ++rr) {
            cst[rr].x = (unsigned int)f2bf(acc[0][rr]) | ((unsigned int)f2bf(acc[1][rr]) << 16);
            cst[rr].y = (unsigned int)f2bf(acc[2][rr]) | ((unsigned int)f2bf(acc[3][rr]) << 16);
        }
        #pragma unroll
        for (int j = 0; j < 4; ++j) ra[j] = na[j];
    }
    #pragma unroll
    for (int rr = 0; rr < 4; ++rr) {         // last iteration's C
        const int bq = 16 * wv + 4 * q + rr;
        *(uint2*)(xh + (((size_t)o * NB + bq) * NI + (ig * 8 + 7)) * ND + 4 * c) = cst[rr];
    }
    #pragma unroll
    for (int rr = 0; rr < 4; ++rr) {         // s0 partials: [b][o][d'] layout
        const int bq = 16 * wv + 4 * q + rr;
        float* sp = s0 + ((size_t)bq * NO + o) * ND + 4 * c;
        #pragma unroll
        for (int td = 0; td < 4; ++td) atomicAdd(sp + td, psum[td][rr]);
    }
}

// Squash s -> out vector, update osum (running sum of outs). One wave per (b,o)
// row of 64 d'-elements. STEP 0: scale by 1/32 (uniform softmax), osum = out.
// STEP 1: osum += out. STEP 2: final output with d' -> d remap.
template<int STEP>
__global__ __launch_bounds__(256) void k_sq(const float* __restrict__ s,
                                            float* __restrict__ osum,
                                            float* __restrict__ outp) {
    const int t = threadIdx.x;
    const int wid = blockIdx.x * 4 + (t >> 6);   // = b*32 + o
    const int l = t & 63;                        // = d'
    float sv = s[(size_t)wid * ND + l];
    if (STEP == 0) sv *= 0.03125f;
    float s2 = sv * sv;
    #pragma unroll
    for (int m = 1; m < 64; m <<= 1) s2 += __shfl_xor(s2, m);
    const float n = sqrtf(s2);
    const float ov = sv * (s2 / (1.0f + s2)) / (n + 1e-8f);
    if (STEP == 0) osum[(size_t)wid * ND + l] = ov;
    if (STEP == 1) osum[(size_t)wid * ND + l] += ov;
    if (STEP == 2) outp[(size_t)wid * ND + 16 * (l & 3) + (l >> 2)] = ov;
}

// Routing pass, block = (b, i-chunk of 16) covering ALL 32 o -> softmax over o
// is block-local; logits are never materialized (b_k = xh . osum, osum = running
// sum of squashed outputs). Thread (o = t>>3, dg = t&7) holds the 16 rows'
// d'-octet in registers (16 x uint4 = 64 VGPR). Emits fp32 atomic partials of
// the c-weighted sum into s_out[b][o][d'].
__global__ __launch_bounds__(256, 4) void k_rt(const unsigned short* __restrict__ xh,
                                               const float* __restrict__ osum,
                                               float* __restrict__ s_out) {
    __shared__ float pS[NO][16];
    __shared__ float mS[16];
    __shared__ float zS[16];
    const int t  = threadIdx.x;
    const int b  = blockIdx.x >> 5;
    const int ic = blockIdx.x & 31;
    const int o  = t >> 3;
    const int dg = t & 7;

    const unsigned short* src = xh + (((size_t)o * NB + b) * NI + ic * 16) * ND + dg * 8;
    uint4 rw[16];
    #pragma unroll
    for (int ii = 0; ii < 16; ++ii)
        rw[ii] = *(const uint4*)(src + (size_t)ii * ND);

    const float* op = osum + ((size_t)b * NO + o) * ND + dg * 8;
    float os[8];
    *(float4*)&os[0] = *(const float4*)op;
    *(float4*)&os[4] = *(const float4*)(op + 4);

    // p[o,ii] = logit = sum_d' xh . osum  (8-local dot + 3-level tree over dg)
    float pp[16];
    #pragma unroll
    for (int ii = 0; ii < 16; ++ii) {
        float a = blo(rw[ii].x) * os[0] + bhi(rw[ii].x) * os[1]
                + blo(rw[ii].y) * os[2] + bhi(rw[ii].y) * os[3]
                + blo(rw[ii].z) * os[4] + bhi(rw[ii].z) * os[5]
                + blo(rw[ii].w) * os[6] + bhi(rw[ii].w) * os[7];
        a += __shfl_xor(a, 1);
        a += __shfl_xor(a, 2);
        a += __shfl_xor(a, 4);
        pp[ii] = a;                          // every lane in o-group has full p
    }
    if (dg == 0) {
        #pragma unroll
        for (int ii = 0; ii < 16; ii += 4) {
            float4 v; v.x = pp[ii]; v.y = pp[ii + 1]; v.z = pp[ii + 2]; v.w = pp[ii + 3];
            *(float4*)&pS[o][ii] = v;
        }
    }
    __syncthreads();

    // softmax stats over o per i-column (redundant across threads, 16 write)
    {
        const int ii = t & 15;
        float m = pS[0][ii];
        #pragma unroll
        for (int oo = 1; oo < NO; ++oo) m = fmaxf(m, pS[oo][ii]);
        float Z = 0.f;
        #pragma unroll
        for (int oo = 0; oo < NO; ++oo) Z += __expf(pS[oo][ii] - m);
        if (t < 16) { mS[ii] = m; zS[ii] = 1.0f / Z; }
    }
    __syncthreads();

    // c-weighted partial sum over this chunk's 16 rows; each thread owns its
    // (o, d'-octet) -> no cross-thread reduce, straight to atomics.
    float sc[8] = {0, 0, 0, 0, 0, 0, 0, 0};
    #pragma unroll
    for (int ii = 0; ii < 16; ++ii) {
        const float cw = __expf(pp[ii] - mS[ii]) * zS[ii];
        sc[0] += cw * blo(rw[ii].x); sc[1] += cw * bhi(rw[ii].x);
        sc[2] += cw * blo(rw[ii].y); sc[3] += cw * bhi(rw[ii].y);
        sc[4] += cw * blo(rw[ii].z); sc[5] += cw * bhi(rw[ii].z);
        sc[6] += cw * blo(rw[ii].w); sc[7] += cw * bhi(rw[ii].w);
    }
    float* sp = s_out + ((size_t)b * NO + o) * ND + dg * 8;
    #pragma unroll
    for (int j = 0; j < 8; ++j) atomicAdd(sp + j, sc[j]);
}

extern "C" void kernel_launch(void* const* d_in, const int* in_sizes, int n_in,
                              void* d_out, int out_size, void* d_ws, size_t ws_size,
                              hipStream_t stream) {
    const float* x = (const float*)d_in[0];        // [64,512,64] fp32
    const float* w = (const float*)d_in[1];        // [32,512,64,64] fp32
    float* outp = (float*)d_out;                   // [64,32,64] fp32

    char* ws = (char*)d_ws;
    unsigned short* xh = (unsigned short*)ws;              // 128 MiB bf16 xh[o][b][i][d']
    float* s0   = (float*)(ws + (size_t)134217728);        // 512 KiB [b][o][d']
    float* s1   = s0 + 131072;                             // 512 KiB
    float* s2   = s1 + 131072;                             // 512 KiB
    float* osum = s2 + 131072;                             // 512 KiB running sum of outs

    hipMemsetAsync(s0, 0, 3 * 524288, stream);             // zero atomic accumulators
    k_gemm<<<dim3(2048), dim3(256), 0, stream>>>(x, w, xh, s0);
    k_sq<0><<<dim3(512), dim3(256), 0, stream>>>(s0, osum, nullptr);
    k_rt<<<dim3(2048), dim3(256), 0, stream>>>(xh, osum, s1);
    k_sq<1><<<dim3(512), dim3(256), 0, stream>>>(s1, osum, nullptr);
    k_rt<<<dim3(2048), dim3(256), 0, stream>>>(xh, osum, s2);
    k_sq<2><<<dim3(512), dim3(256), 0, stream>>>(s2, osum, outp);
}